// Round 5
// baseline (149.567 us; speedup 1.0000x reference)
//
#include <hip/hip_runtime.h>

// Problem constants (match reference)
#define BB   8
#define CC   64
#define HH   256
#define WW   512
#define BND  64   // BOUNDARY, direction 'lr'

typedef float f32x4 __attribute__((ext_vector_type(4)));

// One block per (b,c, y-pair). Stage the up-to-4 source rows in LDS with
// coalesced float4 loads; each half-block (2 waves) handles one output row,
// 4 px/thread, dwordx4 stores (PLAIN this round — A/B vs non-temporal).
// grid = B*C*H/2 = 65536 blocks of 256 threads.
__global__ __launch_bounds__(256) void warp_feature_kernel(
    const float* __restrict__ disp,      // (B,1,H,W)
    const float* __restrict__ tgt,       // (B,C,H,W)
    float* __restrict__ warped,          // (B,C,H,W)
    float* __restrict__ maskout)         // (B,C,H,W) as 0.0/1.0
{
    __shared__ float rows[4][WW];        // 8 KB

    // XCD-aware bijective swizzle: 65536 % 8 == 0, chunk = 8192 blocks.
    const int nwg   = BB * CC * (HH / 2);
    const int chunk = nwg / 8;
    const int bid0  = blockIdx.x;
    const int bid   = (bid0 % 8) * chunk + (bid0 / 8);

    const int yq    = bid & (HH / 2 - 1);
    const int ybase = yq * 2;
    const int bc    = bid >> 7;          // b*CC + c
    const int b     = bc >> 6;
    const int t     = threadIdx.x;

    const int u7  = t >> 7;              // 0 or 1 (wave-uniform half select)
    const int xpx = (t & 127) * 4;
    const int y   = ybase + u7;

    // ---- hoist disp load: independent of staging, overlap its latency ----
    const f32x4 dv = *reinterpret_cast<const f32x4*>(
        disp + ((size_t)b * HH + y) * WW + xpx);

    // ---- y geometry for both rows (reference arithmetic, fp32) ----
    const float shifty = 127.5f;
    float fyr[2]; int y0cr[2], y1cr[2]; float vy0r[2], vy1r[2];
#pragma unroll
    for (int r = 0; r < 2; ++r) {
        const float yy  = (float)(ybase + r);
        const float gy  = (yy - shifty) / shifty;
        const float iy  = ((gy + 1.0f) * (float)HH - 1.0f) * 0.5f;
        const float y0f = floorf(iy);
        fyr[r]  = iy - y0f;
        const int y0 = (int)y0f;
        const int y1 = y0 + 1;
        vy0r[r] = (y0 >= 0 && y0 <= HH - 1) ? 1.0f : 0.0f;
        vy1r[r] = (y1 >= 0 && y1 <= HH - 1) ? 1.0f : 0.0f;
        y0cr[r] = min(max(y0, 0), HH - 1);
        y1cr[r] = min(max(y1, 0), HH - 1);
    }

    const float* img = tgt + (size_t)bc * (HH * WW);

    // ---- stage 4 rows: slot0=y0c(ya) slot1=y1c(ya) slot2=y0c(yb) slot3=y1c(yb)
    {
        const int pos   = (t & 127) * 4;
        const int ysel0 = u7 ? y1cr[0] : y0cr[0];
        const int ysel1 = u7 ? y1cr[1] : y0cr[1];
        const f32x4 v0 = *reinterpret_cast<const f32x4*>(img + (size_t)ysel0 * WW + pos);
        const f32x4 v1 = *reinterpret_cast<const f32x4*>(img + (size_t)ysel1 * WW + pos);
        *reinterpret_cast<f32x4*>(&rows[u7][pos])     = v0;
        *reinterpret_cast<f32x4*>(&rows[2 + u7][pos]) = v1;
    }
    __syncthreads();

    // ---- each half-block computes one output row, 4 px/thread ----
    const float fy  = u7 ? fyr[1] : fyr[0];
    const float vy0 = u7 ? vy0r[1] : vy0r[0];
    const float vy1 = u7 ? vy1r[1] : vy1r[0];
    const float cy0 = (1.0f - fy) * vy0;         // row-uniform weight factors
    const float cy1 = fy * vy1;
    const float* rowlo = &rows[u7 * 2][0];
    const float* rowhi = &rows[u7 * 2 + 1][0];

    // ix = ((((Xs-255.5)/255.5)+1)*512 - 1)*0.5  ==  Xs*(256/255.5) - 0.5
    const float IXA = 256.0f / 255.5f;

    f32x4 res;
#pragma unroll
    for (int k = 0; k < 4; ++k) {
        const float Xs  = (float)(xpx + k) + dv[k];          // 'lr': X + disp
        const float ix  = fmaf(Xs, IXA, -0.5f);
        const float x0f = floorf(ix);
        const float fx  = ix - x0f;
        const int   x0  = (int)x0f;
        const int   x1  = x0 + 1;
        const float vx0 = (x0 >= 0 && x0 <= WW - 1) ? 1.0f : 0.0f;
        const float vx1 = (x1 >= 0 && x1 <= WW - 1) ? 1.0f : 0.0f;
        const int   x0c = min(max(x0, 0), WW - 1);
        const int   x1c = min(max(x1, 0), WW - 1);

        const float a0 = (1.0f - fx) * vx0;
        const float a1 = fx * vx1;

        const float h0 = fmaf(rowlo[x1c], a1, rowlo[x0c] * a0);
        const float h1 = fmaf(rowhi[x1c], a1, rowhi[x0c] * a0);
        res[k] = fmaf(h1, cy1, h0 * cy0);
    }

    const size_t obase = ((size_t)bc * HH + y) * WW + xpx;
    *reinterpret_cast<f32x4*>(warped + obase) = res;         // plain store (A/B)

    // mask: x < 448; xpx multiple of 4, 448 % 4 == 0 -> quad-uniform
    const float mval = (xpx < (WW - BND)) ? 1.0f : 0.0f;
    f32x4 mv = { mval, mval, mval, mval };
    *reinterpret_cast<f32x4*>(maskout + obase) = mv;         // plain store (A/B)
}

extern "C" void kernel_launch(void* const* d_in, const int* in_sizes, int n_in,
                              void* d_out, int out_size, void* d_ws, size_t ws_size,
                              hipStream_t stream) {
    const float* disp = (const float*)d_in[0];
    const float* tgt  = (const float*)d_in[1];
    float* warped  = (float*)d_out;
    float* maskout = (float*)d_out + (size_t)BB * CC * HH * WW;

    const int grid = BB * CC * (HH / 2);         // 65536
    hipLaunchKernelGGL(warp_feature_kernel, dim3(grid), dim3(256), 0, stream,
                       disp, tgt, warped, maskout);
}

// Round 6
// 113.321 us; speedup vs baseline: 1.3198x; 1.3198x over previous
//
#include <hip/hip_runtime.h>

// Problem constants (match reference)
#define BB   8
#define CC   64
#define HH   256
#define WW   512
#define BND  64   // BOUNDARY, direction 'lr'

typedef float f32x4 __attribute__((ext_vector_type(4)));

// One block per (b,c, y-pair). Stage the up-to-4 source rows in LDS with
// coalesced float4 loads; each half-block (2 waves) handles one output row,
// 4 px/thread, dwordx4 NON-TEMPORAL stores (A/B'd: NT is +18% vs plain —
// write-only outputs must not allocate L2/L3, preserving cache for tgt reads).
// grid = B*C*H/2 = 65536 blocks of 256 threads.
__global__ __launch_bounds__(256) void warp_feature_kernel(
    const float* __restrict__ disp,      // (B,1,H,W)
    const float* __restrict__ tgt,       // (B,C,H,W)
    float* __restrict__ warped,          // (B,C,H,W)
    float* __restrict__ maskout)         // (B,C,H,W) as 0.0/1.0
{
    __shared__ float rows[4][WW];        // 8 KB

    // XCD-aware bijective swizzle: 65536 % 8 == 0, chunk = 8192 blocks.
    const int nwg   = BB * CC * (HH / 2);
    const int chunk = nwg / 8;
    const int bid0  = blockIdx.x;
    const int bid   = (bid0 % 8) * chunk + (bid0 / 8);

    const int yq    = bid & (HH / 2 - 1);
    const int ybase = yq * 2;
    const int bc    = bid >> 7;          // b*CC + c
    const int b     = bc >> 6;
    const int t     = threadIdx.x;

    const int u7  = t >> 7;              // 0 or 1 (wave-uniform half select)
    const int xpx = (t & 127) * 4;
    const int y   = ybase + u7;

    // ---- hoist disp load: independent of staging, overlap its latency ----
    const f32x4 dv = *reinterpret_cast<const f32x4*>(
        disp + ((size_t)b * HH + y) * WW + xpx);

    // ---- y geometry for both rows (reference arithmetic, fp32) ----
    const float shifty = 127.5f;
    float fyr[2]; int y0cr[2], y1cr[2]; float vy0r[2], vy1r[2];
#pragma unroll
    for (int r = 0; r < 2; ++r) {
        const float yy  = (float)(ybase + r);
        const float gy  = (yy - shifty) / shifty;
        const float iy  = ((gy + 1.0f) * (float)HH - 1.0f) * 0.5f;
        const float y0f = floorf(iy);
        fyr[r]  = iy - y0f;
        const int y0 = (int)y0f;
        const int y1 = y0 + 1;
        vy0r[r] = (y0 >= 0 && y0 <= HH - 1) ? 1.0f : 0.0f;
        vy1r[r] = (y1 >= 0 && y1 <= HH - 1) ? 1.0f : 0.0f;
        y0cr[r] = min(max(y0, 0), HH - 1);
        y1cr[r] = min(max(y1, 0), HH - 1);
    }

    const float* img = tgt + (size_t)bc * (HH * WW);

    // ---- stage 4 rows: slot0=y0c(ya) slot1=y1c(ya) slot2=y0c(yb) slot3=y1c(yb)
    {
        const int pos   = (t & 127) * 4;
        const int ysel0 = u7 ? y1cr[0] : y0cr[0];
        const int ysel1 = u7 ? y1cr[1] : y0cr[1];
        const f32x4 v0 = *reinterpret_cast<const f32x4*>(img + (size_t)ysel0 * WW + pos);
        const f32x4 v1 = *reinterpret_cast<const f32x4*>(img + (size_t)ysel1 * WW + pos);
        *reinterpret_cast<f32x4*>(&rows[u7][pos])     = v0;
        *reinterpret_cast<f32x4*>(&rows[2 + u7][pos]) = v1;
    }
    __syncthreads();

    // ---- each half-block computes one output row, 4 px/thread ----
    const float fy  = u7 ? fyr[1] : fyr[0];
    const float vy0 = u7 ? vy0r[1] : vy0r[0];
    const float vy1 = u7 ? vy1r[1] : vy1r[0];
    const float cy0 = (1.0f - fy) * vy0;         // row-uniform weight factors
    const float cy1 = fy * vy1;
    const float* rowlo = &rows[u7 * 2][0];
    const float* rowhi = &rows[u7 * 2 + 1][0];

    // ix = ((((Xs-255.5)/255.5)+1)*512 - 1)*0.5  ==  Xs*(256/255.5) - 0.5
    const float IXA = 256.0f / 255.5f;

    f32x4 res;
#pragma unroll
    for (int k = 0; k < 4; ++k) {
        const float Xs  = (float)(xpx + k) + dv[k];          // 'lr': X + disp
        const float ix  = fmaf(Xs, IXA, -0.5f);
        const float x0f = floorf(ix);
        const float fx  = ix - x0f;
        const int   x0  = (int)x0f;
        const int   x1  = x0 + 1;
        const float vx0 = (x0 >= 0 && x0 <= WW - 1) ? 1.0f : 0.0f;
        const float vx1 = (x1 >= 0 && x1 <= WW - 1) ? 1.0f : 0.0f;
        const int   x0c = min(max(x0, 0), WW - 1);
        const int   x1c = min(max(x1, 0), WW - 1);

        const float a0 = (1.0f - fx) * vx0;
        const float a1 = fx * vx1;

        const float h0 = fmaf(rowlo[x1c], a1, rowlo[x0c] * a0);
        const float h1 = fmaf(rowhi[x1c], a1, rowhi[x0c] * a0);
        res[k] = fmaf(h1, cy1, h0 * cy0);
    }

    const size_t obase = ((size_t)bc * HH + y) * WW + xpx;
    __builtin_nontemporal_store(res, reinterpret_cast<f32x4*>(warped + obase));

    // mask: x < 448; xpx multiple of 4, 448 % 4 == 0 -> quad-uniform
    const float mval = (xpx < (WW - BND)) ? 1.0f : 0.0f;
    f32x4 mv = { mval, mval, mval, mval };
    __builtin_nontemporal_store(mv, reinterpret_cast<f32x4*>(maskout + obase));
}

extern "C" void kernel_launch(void* const* d_in, const int* in_sizes, int n_in,
                              void* d_out, int out_size, void* d_ws, size_t ws_size,
                              hipStream_t stream) {
    const float* disp = (const float*)d_in[0];
    const float* tgt  = (const float*)d_in[1];
    float* warped  = (float*)d_out;
    float* maskout = (float*)d_out + (size_t)BB * CC * HH * WW;

    const int grid = BB * CC * (HH / 2);         // 65536
    hipLaunchKernelGGL(warp_feature_kernel, dim3(grid), dim3(256), 0, stream,
                       disp, tgt, warped, maskout);
}